// Round 6
// baseline (175.030 us; speedup 1.0000x reference)
//
#include <hip/hip_runtime.h>
#include <math.h>
#include <stdint.h>

// Rotated IoU loss, mixed fp64/fp32.
// fp64 spine: corners (poly sincos), intersection num/den (cancellation-critical),
//             shoelace accumulation (fp64 fma of fp32 products).
// fp32: in-box tests, masks (compares of fp64-computed values), vertex coords,
//       masked mean, pseudo-angle keys, iou + log.
// Sort: packed u32 key (27-bit sortable-float pseudo-angle + 5-bit index; stable
//       ties like np.argsort) with fp32 (x,y) payload carried in REGISTERS
//       (round 5's LDS gather capped residency at 3 waves/SIMD — reverted).
// All arrays statically indexed -> pure VGPRs, no scratch, no LDS tiles.

__device__ __forceinline__ float rcp_nr(float x) {
  float r = __builtin_amdgcn_rcpf(x);
  return r * (2.0f - x * r);   // 1 Newton step: ~1 ulp
}

__device__ __forceinline__ void cswapf(bool sw, float& a, float& b) {
  const float t = a; a = sw ? b : a; b = sw ? t : b;
}

// |x| <= ~1.88 guaranteed (pred angle in (-pi/2,pi/2), target += +-0.3).
// Taylor to x^21 / x^22: remainder < 1e-16 relative at |x|=1.88.
__device__ __forceinline__ void sincos_poly(double x, double& s, double& c) {
  const double z = x * x;
  double ps = 1.0 / 51090942171709440000.0;          // 1/21!
  ps = fma(ps, z, -1.0 / 121645100408832000.0);      // -1/19!
  ps = fma(ps, z,  1.0 / 355687428096000.0);
  ps = fma(ps, z, -1.0 / 1307674368000.0);
  ps = fma(ps, z,  1.0 / 6227020800.0);
  ps = fma(ps, z, -1.0 / 39916800.0);
  ps = fma(ps, z,  1.0 / 362880.0);
  ps = fma(ps, z, -1.0 / 5040.0);
  ps = fma(ps, z,  1.0 / 120.0);
  ps = fma(ps, z, -1.0 / 6.0);
  ps = fma(ps, z,  1.0);
  s = x * ps;
  double pc = -1.0 / 1124000727777607680000.0;       // -1/22!
  pc = fma(pc, z,  1.0 / 2432902008176640000.0);     // 1/20!
  pc = fma(pc, z, -1.0 / 6402373705728000.0);
  pc = fma(pc, z,  1.0 / 20922789888000.0);
  pc = fma(pc, z, -1.0 / 87178291200.0);
  pc = fma(pc, z,  1.0 / 479001600.0);
  pc = fma(pc, z, -1.0 / 3628800.0);
  pc = fma(pc, z,  1.0 / 40320.0);
  pc = fma(pc, z, -1.0 / 720.0);
  pc = fma(pc, z,  1.0 / 24.0);
  pc = fma(pc, z, -0.5);
  pc = fma(pc, z,  1.0);
  c = pc;
}

__global__ __launch_bounds__(256, 4) void riou_loss_kernel(
    const float* __restrict__ pred, const float* __restrict__ tgt,
    float* __restrict__ out, int N, float invN)
{
  __shared__ float smem[4];

  const int i = blockIdx.x * 256 + threadIdx.x;
  float loss = 0.0f;
  if (i < N) {
    const float* p = pred + (size_t)i * 5;
    const float* t = tgt + (size_t)i * 5;
    const double px = (double)p[0], py = (double)p[1], pw = (double)p[2],
                 ph = (double)p[3], pa = (double)p[4];
    const double tx = (double)t[0], ty = (double)t[1], tw = (double)t[2],
                 th = (double)t[3], ta = (double)t[4];

    // --- fp64 corners ---
    const double SX[4] = {0.5, -0.5, -0.5, 0.5};
    const double SY[4] = {0.5, 0.5, -0.5, -0.5};
    double c1x[4], c1y[4], c2x[4], c2y[4];
    {
      double sa, ca; sincos_poly(pa, sa, ca);
      #pragma unroll
      for (int k = 0; k < 4; k++) {
        const double dx = SX[k] * pw, dy = SY[k] * ph;
        c1x[k] = dx * ca - dy * sa + px;
        c1y[k] = dx * sa + dy * ca + py;
      }
    }
    {
      double sa, ca; sincos_poly(ta, sa, ca);
      #pragma unroll
      for (int k = 0; k < 4; k++) {
        const double dx = SX[k] * tw, dy = SY[k] * th;
        c2x[k] = dx * ca - dy * sa + tx;
        c2y[k] = dx * sa + dy * ca + ty;
      }
    }

    // fp32 vertex bank (static-indexed registers): 0..3 c1, 4..7 c2, 8..23 inters
    float fvx[24], fvy[24];
    #pragma unroll
    for (int k = 0; k < 4; k++) {
      fvx[k] = (float)c1x[k]; fvy[k] = (float)c1y[k];
      fvx[4 + k] = (float)c2x[k]; fvy[4 + k] = (float)c2y[k];
    }

    uint32_t vbit = 0;                       // valid-vertex bitmask
    float sxm = 0.0f, sym = 0.0f, nvf = 0.0f;

    // --- in-box tests (fp32; tolerance 1e-6 >> fp32 test error ~1e-7) ---
    {  // c1 corners inside c2
      const float ax = fvx[4], ay = fvy[4];
      const float abx = fvx[5] - ax, aby = fvy[5] - ay;
      const float adx = fvx[7] - ax, ady = fvy[7] - ay;
      const float idab = rcp_nr(abx * abx + aby * aby);
      const float idad = rcp_nr(adx * adx + ady * ady);
      #pragma unroll
      for (int k = 0; k < 4; k++) {
        const float amx = fvx[k] - ax, amy = fvy[k] - ay;
        const float pab = (abx * amx + aby * amy) * idab;
        const float pad = (adx * amx + ady * amy) * idad;
        const bool in2 = (pab > -1e-6f) && (pab < 1.0f + 1e-6f) &&
                         (pad > -1e-6f) && (pad < 1.0f + 1e-6f);
        vbit |= in2 ? (1u << k) : 0u;
        sxm += in2 ? fvx[k] : 0.0f;
        sym += in2 ? fvy[k] : 0.0f;
        nvf += in2 ? 1.0f : 0.0f;
      }
    }
    {  // c2 corners inside c1
      const float ax = fvx[0], ay = fvy[0];
      const float abx = fvx[1] - ax, aby = fvy[1] - ay;
      const float adx = fvx[3] - ax, ady = fvy[3] - ay;
      const float idab = rcp_nr(abx * abx + aby * aby);
      const float idad = rcp_nr(adx * adx + ady * ady);
      #pragma unroll
      for (int k = 0; k < 4; k++) {
        const float amx = fvx[4 + k] - ax, amy = fvy[4 + k] - ay;
        const float pab = (abx * amx + aby * amy) * idab;
        const float pad = (adx * amx + ady * amy) * idad;
        const bool in1 = (pab > -1e-6f) && (pab < 1.0f + 1e-6f) &&
                         (pad > -1e-6f) && (pad < 1.0f + 1e-6f);
        vbit |= in1 ? (1u << (4 + k)) : 0u;
        sxm += in1 ? fvx[4 + k] : 0.0f;
        sym += in1 ? fvy[4 + k] : 0.0f;
        nvf += in1 ? 1.0f : 0.0f;
      }
    }

    // --- edge-edge intersections: fp64 num/den, fp32 masks + points ---
    double e1x[4], e1y[4], e2x[4], e2y[4];
    float f1x[4], f1y[4];
    #pragma unroll
    for (int k = 0; k < 4; k++) {
      e1x[k] = c1x[(k + 1) & 3] - c1x[k]; e1y[k] = c1y[(k + 1) & 3] - c1y[k];
      e2x[k] = c2x[(k + 1) & 3] - c2x[k]; e2y[k] = c2y[(k + 1) & 3] - c2y[k];
      f1x[k] = (float)e1x[k]; f1y[k] = (float)e1y[k];
    }
    #pragma unroll
    for (int a = 0; a < 4; a++) {
      #pragma unroll
      for (int b = 0; b < 4; b++) {
        const double dx13 = c1x[a] - c2x[b], dy13 = c1y[a] - c2y[b];
        const double num  = e2y[b] * e1x[a] - e2x[b] * e1y[a];
        const double dent = e2x[b] * dy13 - e2y[b] * dx13;
        const double denu = e1x[a] * dy13 - e1y[a] * dx13;
        const float numf = (float)num, dtf = (float)dent, duf = (float)denu;
        // t,u strictly in (0,1): sign tests, no division
        const bool mk = (numf > 0.0f)
            ? ((dtf > 0.0f) && (dtf < numf) && (duf > 0.0f) && (duf < numf))
            : ((numf < 0.0f) && (dtf < 0.0f) && (dtf > numf) && (duf < 0.0f) && (duf > numf));
        // ref quirk: t = den_t / (num + 1e-8)
        const float tt = dtf * rcp_nr(numf + 1e-8f);
        const float ix = fvx[a] + tt * f1x[a];
        const float iy = fvy[a] + tt * f1y[a];
        const int id = 8 + a * 4 + b;
        fvx[id] = ix; fvy[id] = iy;
        vbit |= mk ? (1u << id) : 0u;
        sxm += mk ? ix : 0.0f;
        sym += mk ? iy : 0.0f;
        nvf += mk ? 1.0f : 0.0f;
      }
    }

    // --- masked mean + packed sort keys ---
    const float invn = 1.0f / fmaxf(nvf, 1.0f);
    const float mx = sxm * invn, my = sym * invn;
    uint32_t s[24];
    #pragma unroll
    for (int k = 0; k < 24; k++) {
      const float xf = fvx[k] - mx, yf = fvy[k] - my;
      const float den = fabsf(xf) + fabsf(yf);
      const float pp = (den == 0.0f) ? 1.0f : xf * __builtin_amdgcn_rcpf(den);
      const float ky = (yf >= 0.0f) ? -pp : (pp - 2.0f);  // monotone in atan2 over (-pi,pi]
      const uint32_t u = __float_as_uint(ky);
      const uint32_t srt = u ^ ((u & 0x80000000u) ? 0xFFFFFFFFu : 0x80000000u);
      const bool valid = (vbit >> k) & 1u;
      // 27-bit key + 5-bit index (stable ties, like np.argsort); invalid -> max class
      s[k] = valid ? ((srt & 0xFFFFFFE0u) | (uint32_t)k) : (0xFFFFFFE0u | (uint32_t)k);
    }

    // --- Batcher odd-even mergesort, n=32 pruned to 24 wires, payload in regs ---
    #pragma unroll
    for (int pp2 = 1; pp2 < 32; pp2 <<= 1) {
      #pragma unroll
      for (int kk = pp2; kk >= 1; kk >>= 1) {
        #pragma unroll
        for (int j = kk % pp2; j <= 31 - kk; j += 2 * kk) {
          #pragma unroll
          for (int q = 0; q <= ((kk - 1 < 31 - j - kk) ? kk - 1 : 31 - j - kk); q++) {
            if ((q + j) / (2 * pp2) == (q + j + kk) / (2 * pp2)) {
              const int a = q + j, b = q + j + kk;
              if (b < 24) {
                const bool sw = s[b] < s[a];
                const uint32_t lo = min(s[a], s[b]);
                const uint32_t hi = max(s[a], s[b]);
                s[a] = lo; s[b] = hi;
                cswapf(sw, fvx[a], fvx[b]);
                cswapf(sw, fvy[a], fvy[b]);
              }
            }
          }
        }
      }
    }

    // --- replace invalid (keys >= 0xFFFFFFE0 sort last) with sorted[0] ---
    const float v0x = fvx[0], v0y = fvy[0];
    #pragma unroll
    for (int k = 1; k < 24; k++) {
      const bool inv = s[k] >= 0xFFFFFFE0u;
      fvx[k] = inv ? v0x : fvx[k];
      fvy[k] = inv ? v0y : fvy[k];
    }

    // --- shoelace: fp32 coords, fp64 fma accumulation (cyclic) ---
    double cr = 0.0;
    #pragma unroll
    for (int k = 0; k < 24; k++) {
      const int kn = (k + 1) % 24;
      cr = fma((double)fvx[k], (double)fvy[kn], cr);
      cr = fma(-(double)fvy[k], (double)fvx[kn], cr);
    }

    const double inter = fabs(cr) * 0.5;
    const double uni = pw * ph + tw * th - inter;
    float iou = (float)inter / (float)uni;
    iou = fminf(fmaxf(iou, 0.0f), 1.0f);
    iou = fmaxf(iou, 1e-6f);
    loss = -logf(iou);
  }

  // --- block reduction (fp32) + one scaled atomic per block ---
  #pragma unroll
  for (int off = 32; off > 0; off >>= 1)
    loss += __shfl_down(loss, off, 64);
  const int lane = threadIdx.x & 63, wid = threadIdx.x >> 6;
  if (lane == 0) smem[wid] = loss;
  __syncthreads();
  if (threadIdx.x == 0)
    atomicAdd(out, (smem[0] + smem[1] + smem[2] + smem[3]) * invN);
}

extern "C" void kernel_launch(void* const* d_in, const int* in_sizes, int n_in,
                              void* d_out, int out_size, void* d_ws, size_t ws_size,
                              hipStream_t stream) {
  const float* pred = (const float*)d_in[0];
  const float* tgt  = (const float*)d_in[1];
  float* out = (float*)d_out;
  const int N = in_sizes[0] / 5;
  const int nb = (N + 255) / 256;

  hipMemsetAsync(out, 0, sizeof(float), stream);
  riou_loss_kernel<<<nb, 256, 0, stream>>>(pred, tgt, out, N, (float)(1.0 / (double)N));
}